// Round 4
// baseline (222.818 us; speedup 1.0000x reference)
//
#include <hip/hip_runtime.h>
#include <stdint.h>

#define KNN 16
#define GRES 16
#define NCELLS (GRES * GRES * GRES)
// Cell size 9/16 is exact in fp32; grid origin -4.5 = -8*s, so every face
// position (i-8)*s is an EXACT fp32 value -> pruning bounds have no face error.
#define GRID_S 0.5625f
#define GRID_INV 1.7777778f  // 16/9; 1ulp cell-assignment slack is covered by
                             // the stop margin, and the SAME formula is used
                             // by count/scatter/knn (consistency is what the
                             // pruning bound needs)

typedef float vfloat4 __attribute__((ext_vector_type(4)));

__device__ __forceinline__ int cell_coord(float x) {
    int i = (int)floorf((x + 4.5f) * GRID_INV);
    return min(max(i, 0), GRES - 1);
}

// Map float to a uint32 whose unsigned order matches the float order.
__device__ __forceinline__ uint32_t fkey(float f) {
    uint32_t u = __float_as_uint(f);
    return (u & 0x80000000u) ? ~u : (u | 0x80000000u);
}

// Inverse of fkey on the high word of a u64 key -> float dist (+inf for the
// ~0ull sentinel so "dist < tauf" admits everything while list not full).
__device__ __forceinline__ float inv_fkey_hi(unsigned long long key) {
    const uint32_t k = (uint32_t)(key >> 32);
    if (k == 0xFFFFFFFFu) return __builtin_inff();
    const uint32_t u = (k & 0x80000000u) ? (k ^ 0x80000000u) : ~k;
    return __uint_as_float(u);
}

// u64 broadcast from wave-uniform lane l: two v_readlane.
__device__ __forceinline__ unsigned long long bcast64(unsigned long long x, int l) {
    const uint32_t lo = (uint32_t)__builtin_amdgcn_readlane((int)(uint32_t)x, l);
    const uint32_t hi = (uint32_t)__builtin_amdgcn_readlane((int)(uint32_t)(x >> 32), l);
    return ((unsigned long long)hi << 32) | lo;
}

// u64 lane shift-up-by-1 within each 16-lane DPP row (row_shr:1). Lane 0 gets
// 0 (bound_ctrl), masked by callers via lane==0 select. VALU-only.
__device__ __forceinline__ unsigned long long shup1_64(unsigned long long x) {
    const uint32_t lo = (uint32_t)__builtin_amdgcn_update_dpp(
        0, (int)(uint32_t)x, 0x111, 0xF, 0xF, true);
    const uint32_t hi = (uint32_t)__builtin_amdgcn_update_dpp(
        0, (int)(uint32_t)(x >> 32), 0x111, 0xF, 0xF, true);
    return ((unsigned long long)hi << 32) | lo;
}

// ---------------- grid build ----------------

__global__ __launch_bounds__(256) void zero_kernel(int* __restrict__ counts) {
    const int i = blockIdx.x * 256 + threadIdx.x;
    if (i < NCELLS) counts[i] = 0;
}

__global__ __launch_bounds__(256) void count_kernel(
    const float* __restrict__ xyz, int* __restrict__ counts, int n)
{
    const int i = blockIdx.x * 256 + threadIdx.x;
    if (i >= n) return;
    const int cx = cell_coord(xyz[3 * i + 0]);
    const int cy = cell_coord(xyz[3 * i + 1]);
    const int cz = cell_coord(xyz[3 * i + 2]);
    atomicAdd(&counts[(cz * GRES + cy) * GRES + cx], 1);
}

// Exclusive scan of NCELLS=4096 counts; single 1024-thread block, 4/thread.
__global__ __launch_bounds__(1024) void scan_kernel(
    const int* __restrict__ counts, int* __restrict__ offs, int* __restrict__ cursor)
{
    __shared__ int lds[1024];
    const int t = threadIdx.x;
    int c[4];
    int s = 0;
#pragma unroll
    for (int u = 0; u < 4; ++u) { c[u] = counts[t * 4 + u]; s += c[u]; }
    lds[t] = s;
    __syncthreads();
    for (int d = 1; d < 1024; d <<= 1) {
        const int v = (t >= d) ? lds[t - d] : 0;
        __syncthreads();
        lds[t] += v;
        __syncthreads();
    }
    int run = (t == 0) ? 0 : lds[t - 1];
#pragma unroll
    for (int u = 0; u < 4; ++u) {
        const int idx = t * 4 + u;
        offs[idx] = run;
        cursor[idx] = run;
        run += c[u];
    }
    if (t == 1023) offs[NCELLS] = run;
}

// Scatter points into cell-sorted order as (x, y, z, bitcast(orig_idx)).
// Within-cell order is nondeterministic (atomics) — benign: the top-16 of an
// examined SET under exact total-order u64 keys is order-independent, and
// stop checks happen only at ring boundaries (set-defined tau).
__global__ __launch_bounds__(256) void scatter_kernel(
    const float* __restrict__ xyz, int* __restrict__ cursor,
    vfloat4* __restrict__ sorted, int n)
{
    const int i = blockIdx.x * 256 + threadIdx.x;
    if (i >= n) return;
    const float x = xyz[3 * i + 0];
    const float y = xyz[3 * i + 1];
    const float z = xyz[3 * i + 2];
    const int c = (cell_coord(z) * GRES + cell_coord(y)) * GRES + cell_coord(x);
    const int pos = atomicAdd(&cursor[c], 1);
    vfloat4 v = {x, y, z, __int_as_float(i)};
    sorted[pos] = v;
}

// ---------------- grid-pruned exact kNN ----------------

// Process candidates [st, en) from the sorted table in 64-wide batches:
// exact u64-key ballot + verified serial insert into the wave-distributed
// sorted top-16 (lanes 0..15; tau = lane-15 key = exact running 16th-best).
// r2 is recomputed with the exact reference fp32 op order (bit-identical to
// a precomputed table; verified absmax 0 in earlier rounds with this order).
__device__ __forceinline__ void process_range(
    const vfloat4* __restrict__ sorted, int st, int en, int lane,
    float qx, float qy, float qz, float q2,
    unsigned long long& lkey, unsigned long long& tau, float& tauf)
{
    for (int j0 = st; j0 < en; j0 += 64) {
        const int j = j0 + lane;
        const bool a = j < en;
        const vfloat4 p = sorted[a ? j : j0];
        const uint32_t oi = __float_as_uint(p.w);
        const float r2 = __fadd_rn(__fadd_rn(__fmul_rn(p.x, p.x), __fmul_rn(p.y, p.y)),
                                   __fmul_rn(p.z, p.z));
        const float cr = __fmaf_rn(p.z, qz, __fmaf_rn(p.y, qy, __fmul_rn(p.x, qx)));
        const float dist = __fsub_rn(__fadd_rn(q2, r2), __fmul_rn(2.0f, cr));
        const unsigned long long key = a
            ? (((unsigned long long)fkey(dist) << 32) | oi)
            : ~0ull;
        unsigned long long mask = __ballot(key < tau);
        while (mask) {  // wave-uniform
            const int b = (int)__builtin_ctzll(mask);
            mask &= mask - 1;
            const unsigned long long bk = bcast64(key, b);
            if (bk < tau) {  // re-check: tau may have tightened (uniform)
                const unsigned long long sh = shup1_64(lkey);
                unsigned long long nk;
                if (lkey < bk) nk = lkey;                    // stays
                else nk = (lane == 0 || sh < bk) ? bk : sh;  // insert/shift
                tau = bcast64(nk, 15);  // nk computed by all 64 lanes
                tauf = inv_fkey_hi(tau);
                if (lane < KNN) lkey = nk;
            }
        }
    }
}

// One wave per query, 4 queries per 256-thread block (full 32-wave/CU
// occupancy; no barriers, waves independent). Expanding Chebyshev rings over
// the cell grid; cells contiguous in x are processed as ONE candidate range
// (sorted table is cell-major contiguous). Conservative stop: after examining
// box radius B=R-1, every unexamined point's dist >= g^2 (g = min exact-face
// gap); stop iff tauf < 0.99*g*g - 1e-3 (margin >> total fp error ~3e-5; a
// wrong stop would need 0.01*g^2 + 9.7e-4 < 0, impossible).
__global__ __launch_bounds__(256) void knn_kernel(
    const vfloat4* __restrict__ sorted, const int* __restrict__ offs,
    const float* __restrict__ xyz_cur, int* __restrict__ knn_idx, int n_cur)
{
    const int lane = threadIdx.x & 63;
    const int q = blockIdx.x * 4 + (threadIdx.x >> 6);
    if (q >= n_cur) return;  // wave-uniform

    const float qx = xyz_cur[3 * q + 0];
    const float qy = xyz_cur[3 * q + 1];
    const float qz = xyz_cur[3 * q + 2];
    const float q2 = __fadd_rn(__fadd_rn(__fmul_rn(qx, qx), __fmul_rn(qy, qy)),
                               __fmul_rn(qz, qz));

    const int cx = cell_coord(qx), cy = cell_coord(qy), cz = cell_coord(qz);

    unsigned long long lkey, tau;
    float tauf;

    // ---- warmup: bitonic sort of first <=64 own-cell candidates ----
    const int cid0 = (cz * GRES + cy) * GRES + cx;
    const int st0 = offs[cid0];
    const int en0 = offs[cid0 + 1];
    const int cnt0 = en0 - st0;
    {
        unsigned long long v = ~0ull;
        if (cnt0 > 0) {  // wave-uniform
            const vfloat4 p = sorted[(lane < cnt0) ? (st0 + lane) : st0];
            const uint32_t oi = __float_as_uint(p.w);
            const float r2 = __fadd_rn(__fadd_rn(__fmul_rn(p.x, p.x), __fmul_rn(p.y, p.y)),
                                       __fmul_rn(p.z, p.z));
            const float cr = __fmaf_rn(p.z, qz, __fmaf_rn(p.y, qy, __fmul_rn(p.x, qx)));
            const float dist = __fsub_rn(__fadd_rn(q2, r2), __fmul_rn(2.0f, cr));
            v = (lane < cnt0)
                ? (((unsigned long long)fkey(dist) << 32) | oi)
                : ~0ull;
        }
#pragma unroll
        for (int k = 2; k <= 64; k <<= 1) {
#pragma unroll
            for (int j = k >> 1; j > 0; j >>= 1) {
                const unsigned long long o = __shfl_xor(v, j, 64);
                const bool keepMin = (((lane & k) == 0) == ((lane & j) == 0));
                const bool omin = o < v;
                v = (keepMin == omin) ? o : v;
            }
        }
        lkey = (lane < KNN) ? v : ~0ull;
        tau = bcast64(lkey, 15);
        tauf = inv_fkey_hi(tau);
    }
    // own-cell leftover (cells can hold >64 points)
    if (cnt0 > 64)
        process_range(sorted, st0 + 64, en0, lane, qx, qy, qz, q2, lkey, tau, tauf);

    const int Rmax = max(max(max(cx, GRES - 1 - cx), max(cy, GRES - 1 - cy)),
                         max(cz, GRES - 1 - cz));

    for (int R = 1; R <= GRES - 1; ++R) {
        // stop check vs box radius B = R-1. Faces (i-8)*GRID_S are exact fp32.
        float g = __builtin_inff();
        if (cx - R >= 0)        g = fminf(g, qx - (float)(cx - R + 1 - 8) * GRID_S);
        if (cx + R <= GRES - 1) g = fminf(g, (float)(cx + R - 8) * GRID_S - qx);
        if (cy - R >= 0)        g = fminf(g, qy - (float)(cy - R + 1 - 8) * GRID_S);
        if (cy + R <= GRES - 1) g = fminf(g, (float)(cy + R - 8) * GRID_S - qy);
        if (cz - R >= 0)        g = fminf(g, qz - (float)(cz - R + 1 - 8) * GRID_S);
        if (cz + R <= GRES - 1) g = fminf(g, (float)(cz + R - 8) * GRID_S - qz);
        if (tauf < g * g * 0.99f - 1e-3f) break;  // all unexamined provably worse
        if (R > Rmax) break;                      // whole grid examined

        const int xlo = max(0, cx - R), xhi = min(GRES - 1, cx + R);
        for (int dz = -R; dz <= R; ++dz) {
            const int iz = cz + dz;
            if (iz < 0 || iz > GRES - 1) continue;
            const bool za = (dz == -R) || (dz == R);
            for (int dy = -R; dy <= R; ++dy) {
                const int iy = cy + dy;
                if (iy < 0 || iy > GRES - 1) continue;
                const int row = (iz * GRES + iy) * GRES;
                if (za || (dy == -R) || (dy == R)) {
                    // full x-run: cells row+xlo .. row+xhi are CONTIGUOUS in
                    // the sorted table -> one merged candidate range.
                    process_range(sorted, offs[row + xlo], offs[row + xhi + 1],
                                  lane, qx, qy, qz, q2, lkey, tau, tauf);
                } else {
                    // interior row: only the two x-faces.
                    if (cx - R >= 0)
                        process_range(sorted, offs[row + cx - R], offs[row + cx - R + 1],
                                      lane, qx, qy, qz, q2, lkey, tau, tauf);
                    if (cx + R <= GRES - 1)
                        process_range(sorted, offs[row + cx + R], offs[row + cx + R + 1],
                                      lane, qx, qy, qz, q2, lkey, tau, tauf);
                }
            }
        }
    }

    if (lane < KNN)
        knn_idx[q * KNN + lane] = (int)(lkey & 0xffffffffu);
}

// Verified combine, verbatim: one wave per (query, neighbor-group-of-4).
// Coverage: w in [0, 4*n_cur) -> q = w>>2, jg = (w&3)*4; rows q*16+jg+{0..3}
// — every output row exactly once. Nontemporal stores keep the 134 MB write
// stream from evicting the 8 MB gather table out of L2/LLC.
__global__ __launch_bounds__(256) void combine_kernel(
    const float* __restrict__ feat_prev, const float* __restrict__ feat_cur,
    const int* __restrict__ knn_idx, float* __restrict__ out,
    int n_cur, int c4)
{
    const int w = blockIdx.x * 4 + (threadIdx.x >> 6);
    const int lane = threadIdx.x & 63;
    const int q = w >> 2;
    const int jg = (w & 3) * 4;
    if (q >= n_cur) return;

    int nb[4];
#pragma unroll
    for (int j = 0; j < 4; ++j)
        nb[j] = knn_idx[q * KNN + jg + j];

    const vfloat4* pbase = (const vfloat4*)feat_prev;
    const vfloat4* crow  = (const vfloat4*)feat_cur + (size_t)q * c4;
    const int c8 = 2 * c4;

    for (int i = lane; i < c4; i += 64) {
        const vfloat4 c = crow[i];
        vfloat4 p[4];
#pragma unroll
        for (int j = 0; j < 4; ++j)
            p[j] = pbase[(size_t)nb[j] * c4 + i];

#pragma unroll
        for (int j = 0; j < 4; ++j) {
            vfloat4* orow = (vfloat4*)out + (size_t)(q * KNN + jg + j) * c8;
            __builtin_nontemporal_store(p[j] - c, orow + i);
            __builtin_nontemporal_store(c, orow + c4 + i);
        }
    }
}

extern "C" void kernel_launch(void* const* d_in, const int* in_sizes, int n_in,
                              void* d_out, int out_size, void* d_ws, size_t ws_size,
                              hipStream_t stream) {
    const float* xyz_prev  = (const float*)d_in[0];
    const float* xyz_cur   = (const float*)d_in[1];
    const float* feat_prev = (const float*)d_in[2];
    const float* feat_cur  = (const float*)d_in[3];
    float* out = (float*)d_out;

    const int n_prev = in_sizes[0] / 3;
    const int n_cur  = in_sizes[1] / 3;
    const int C      = in_sizes[2] / n_prev;   // 256

    // d_ws layout (16B-aligned blocks; total ~440 KB, ws is poisoned at
    // 512 MiB by the harness so plenty of room):
    char* w = (char*)d_ws;
    vfloat4* sorted = (vfloat4*)w;                 w += (size_t)n_prev * 16;
    int* counts = (int*)w;                         w += (size_t)NCELLS * 4;
    int* offs   = (int*)w;                         w += (size_t)(NCELLS + 1) * 4 + 12;
    int* cursor = (int*)w;                         w += (size_t)NCELLS * 4;
    int* knn    = (int*)w;

    zero_kernel<<<(NCELLS + 255) / 256, 256, 0, stream>>>(counts);
    count_kernel<<<(n_prev + 255) / 256, 256, 0, stream>>>(xyz_prev, counts, n_prev);
    scan_kernel<<<1, 1024, 0, stream>>>(counts, offs, cursor);
    scatter_kernel<<<(n_prev + 255) / 256, 256, 0, stream>>>(xyz_prev, cursor,
                                                             sorted, n_prev);
    knn_kernel<<<(n_cur + 3) / 4, 256, 0, stream>>>(sorted, offs, xyz_cur, knn, n_cur);

    const int n_waves = n_cur * 4;             // 4 neighbor-rows per wave
    combine_kernel<<<(n_waves + 3) / 4, 256, 0, stream>>>(feat_prev, feat_cur,
                                                          knn, out, n_cur, C / 4);
}

// Round 5
// 199.752 us; speedup vs baseline: 1.1155x; 1.1155x over previous
//
#include <hip/hip_runtime.h>
#include <stdint.h>

#define KNN 16

typedef float vfloat4 __attribute__((ext_vector_type(4)));

// Map float to a uint32 whose unsigned order matches the float order
// (handles tiny negative dists from fp rounding).
__device__ __forceinline__ uint32_t fkey(float f) {
    uint32_t u = __float_as_uint(f);
    return (u & 0x80000000u) ? ~u : (u | 0x80000000u);
}

// Inverse of fkey on the high word of a u64 key -> float dist (+inf for the
// ~0ull sentinel so "dist < tauf" admits everything while list not full).
__device__ __forceinline__ float inv_fkey_hi(unsigned long long key) {
    const uint32_t k = (uint32_t)(key >> 32);
    if (k == 0xFFFFFFFFu) return __builtin_inff();
    const uint32_t u = (k & 0x80000000u) ? (k ^ 0x80000000u) : ~k;
    return __uint_as_float(u);
}

// u64 broadcast from wave-uniform lane l: two v_readlane (no DS-pipe traffic,
// unlike __shfl which lowers to 2x ds_bpermute_b32).
__device__ __forceinline__ unsigned long long bcast64(unsigned long long x, int l) {
    const uint32_t lo = (uint32_t)__builtin_amdgcn_readlane((int)(uint32_t)x, l);
    const uint32_t hi = (uint32_t)__builtin_amdgcn_readlane((int)(uint32_t)(x >> 32), l);
    return ((unsigned long long)hi << 32) | lo;
}

// u64 lane shift-up-by-1 within each 16-lane DPP row (row_shr:1 = 0x111).
// Lanes 1..15 get lane-1..14's value; lane 0 gets 0 (bound_ctrl), masked by
// callers via an explicit lane==0 select; lanes >=16 are discarded by the
// lane<16 list guard. VALU-only.
__device__ __forceinline__ unsigned long long shup1_64(unsigned long long x) {
    const uint32_t lo = (uint32_t)__builtin_amdgcn_update_dpp(
        0, (int)(uint32_t)x, 0x111, 0xF, 0xF, true);
    const uint32_t hi = (uint32_t)__builtin_amdgcn_update_dpp(
        0, (int)(uint32_t)(x >> 32), 0x111, 0xF, 0xF, true);
    return ((unsigned long long)hi << 32) | lo;
}

// Pack xyz_prev into (x, y, z, r2) float4 rows. r2 uses the exact fp32 op
// order of the reference (verified absmax 0 across all prior rounds), so
// downstream distances are bit-identical.
__global__ __launch_bounds__(256) void prep_kernel(
    const float* __restrict__ xyz_prev, vfloat4* __restrict__ P, int n_prev)
{
    const int i = blockIdx.x * 256 + threadIdx.x;
    if (i >= n_prev) return;
    const float x = xyz_prev[3 * i + 0];
    const float y = xyz_prev[3 * i + 1];
    const float z = xyz_prev[3 * i + 2];
    const float r2 = __fadd_rn(__fadd_rn(__fmul_rn(x, x), __fmul_rn(y, y)),
                               __fmul_rn(z, z));
    vfloat4 v = {x, y, z, r2};
    P[i] = v;
}

// ONE wave per query (R0's best-measured frame, 202.0us) + R2's measured
// hot-loop improvements (-4.6us on the 2-wave frame):
//  (a) FLOAT ballot: hot-loop test is one v_cmp_lt_f32 (dist < tauf).
//      EXACTNESS: candidates arrive in increasing idx order and ballot bits
//      are consumed low->high, so every list entry has idx < candidate idx;
//      on a dist tie the candidate's u64 key is ALWAYS larger -> key<tau <=>
//      dist<tauf (strict). dist is never -0.0 (a-b with a>=+0 can't round to
//      -0 in RN) and never NaN; sentinel slots give tauf=+inf. The insert
//      path re-checks with exact u64 keys (fkey(dist)<<32|idx — identical
//      total order to jax.lax.top_k's stable ascending (dist, idx)).
//  (b) pv[4] batching + __launch_bounds__(256,8): VGPR <= 64 -> 8 waves/SIMD
//      (R0's pv[8]+u64 body sat at 4 waves/SIMD).
//  (c) main loop over provably-full 64-wide iterations (8192 % 64 == 0);
//      generic predicated tail kept for safety.
__global__ __launch_bounds__(256, 8) void knn_kernel(
    const vfloat4* __restrict__ P, const float* __restrict__ xyz_cur,
    int* __restrict__ knn_idx, int n_prev, int n_cur)
{
    const int lane = threadIdx.x & 63;
    const int q = blockIdx.x * 4 + (threadIdx.x >> 6);
    if (q >= n_cur) return;  // wave-uniform

    const float qx = xyz_cur[3 * q + 0];
    const float qy = xyz_cur[3 * q + 1];
    const float qz = xyz_cur[3 * q + 2];
    // q2 is a per-query constant (cannot change the argsort); same op order.
    const float q2 = __fadd_rn(__fadd_rn(__fmul_rn(qx, qx), __fmul_rn(qy, qy)),
                               __fmul_rn(qz, qz));

    // ---- warmup: bitonic sort of the first 64 candidates (ascending) ----
    unsigned long long v;
    {
        const int r = lane;
        const vfloat4 p = P[r < n_prev ? r : 0];
        const float cr = __fmaf_rn(p.z, qz, __fmaf_rn(p.y, qy, __fmul_rn(p.x, qx)));
        const float dist = __fsub_rn(__fadd_rn(q2, p.w), __fmul_rn(2.0f, cr));
        v = (r < n_prev)
            ? (((unsigned long long)fkey(dist) << 32) | (uint32_t)r)
            : ~0ull;
    }
#pragma unroll
    for (int k = 2; k <= 64; k <<= 1) {
#pragma unroll
        for (int j = k >> 1; j > 0; j >>= 1) {
            const unsigned long long o = __shfl_xor(v, j, 64);
            const bool keepMin = (((lane & k) == 0) == ((lane & j) == 0));
            const bool omin = o < v;
            v = (keepMin == omin) ? o : v;  // keepMin ? min(v,o) : max(v,o)
        }
    }
    unsigned long long lkey = (lane < KNN) ? v : ~0ull;
    unsigned long long tau = bcast64(lkey, 15);  // EXACT running 16th-best
    float tauf = inv_fkey_hi(tau);               // same value as a float dist

    const int n_full = n_prev >> 6;   // full 64-candidate iterations (incl. t=0)
    int t = 1;
    // main: groups of 4 full iterations, loads issued up front (4-deep MLP).
    for (; t + 3 < n_full; t += 4) {
        vfloat4 pv[4];
#pragma unroll
        for (int u = 0; u < 4; ++u)
            pv[u] = P[((t + u) << 6) + lane];
#pragma unroll
        for (int u = 0; u < 4; ++u) {
            const int rbase = (t + u) << 6;
            const vfloat4 p = pv[u];
            const float cr = __fmaf_rn(p.z, qz, __fmaf_rn(p.y, qy, __fmul_rn(p.x, qx)));
            const float dist = __fsub_rn(__fadd_rn(q2, p.w), __fmul_rn(2.0f, cr));
            unsigned long long mask = __ballot(dist < tauf);
            while (mask) {  // wave-uniform
                const int b = (int)__builtin_ctzll(mask);
                mask &= mask - 1;
                // rebuild lane b's exact u64 key uniformly: 1 readlane + fkey
                const float bd = __uint_as_float(
                    (uint32_t)__builtin_amdgcn_readlane((int)__float_as_uint(dist), b));
                const unsigned long long bk =
                    (((unsigned long long)fkey(bd)) << 32) | (uint32_t)(rbase + b);
                if (bk < tau) {  // exact re-check: tau may have tightened
                    const unsigned long long sh = shup1_64(lkey);
                    unsigned long long nk;
                    if (lkey < bk) nk = lkey;                    // stays
                    else nk = (lane == 0 || sh < bk) ? bk : sh;  // insert/shift
                    tau = bcast64(nk, 15);  // nk computed by all 64 lanes
                    tauf = inv_fkey_hi(tau);
                    if (lane < KNN) lkey = nk;
                }
            }
        }
    }
    // remaining full iterations, single-t body
    for (; t < n_full; ++t) {
        const int rbase = t << 6;
        const vfloat4 p = P[rbase + lane];
        const float cr = __fmaf_rn(p.z, qz, __fmaf_rn(p.y, qy, __fmul_rn(p.x, qx)));
        const float dist = __fsub_rn(__fadd_rn(q2, p.w), __fmul_rn(2.0f, cr));
        unsigned long long mask = __ballot(dist < tauf);
        while (mask) {
            const int b = (int)__builtin_ctzll(mask);
            mask &= mask - 1;
            const float bd = __uint_as_float(
                (uint32_t)__builtin_amdgcn_readlane((int)__float_as_uint(dist), b));
            const unsigned long long bk =
                (((unsigned long long)fkey(bd)) << 32) | (uint32_t)(rbase + b);
            if (bk < tau) {
                const unsigned long long sh = shup1_64(lkey);
                unsigned long long nk;
                if (lkey < bk) nk = lkey;
                else nk = (lane == 0 || sh < bk) ? bk : sh;
                tau = bcast64(nk, 15);
                tauf = inv_fkey_hi(tau);
                if (lane < KNN) lkey = nk;
            }
        }
    }
    // generic partial tail (never taken for n_prev % 64 == 0)
    if (n_prev & 63) {
        const int rbase = n_full << 6;
        const int r = rbase + lane;
        const vfloat4 p = P[r < n_prev ? r : 0];
        const float cr = __fmaf_rn(p.z, qz, __fmaf_rn(p.y, qy, __fmul_rn(p.x, qx)));
        float dist = __fsub_rn(__fadd_rn(q2, p.w), __fmul_rn(2.0f, cr));
        if (r >= n_prev) dist = __builtin_inff();
        unsigned long long mask = __ballot(dist < tauf);
        while (mask) {
            const int b = (int)__builtin_ctzll(mask);
            mask &= mask - 1;
            const float bd = __uint_as_float(
                (uint32_t)__builtin_amdgcn_readlane((int)__float_as_uint(dist), b));
            const unsigned long long bk =
                (((unsigned long long)fkey(bd)) << 32) | (uint32_t)(rbase + b);
            if (bk < tau) {
                const unsigned long long sh = shup1_64(lkey);
                unsigned long long nk;
                if (lkey < bk) nk = lkey;
                else nk = (lane == 0 || sh < bk) ? bk : sh;
                tau = bcast64(nk, 15);
                tauf = inv_fkey_hi(tau);
                if (lane < KNN) lkey = nk;
            }
        }
    }

    if (lane < KNN)
        knn_idx[q * KNN + lane] = (int)(lkey & 0xffffffffu);
}

// Verified combine, verbatim (present in every measurement): one wave per
// (query, neighbor-group-of-4). Coverage: w in [0, 4*n_cur) -> q = w>>2,
// jg = (w&3)*4; rows q*16+jg+{0..3} — every output row exactly once.
// Nontemporal stores keep the 134 MB write stream from evicting the 8 MB
// gather table out of L2/LLC.
__global__ __launch_bounds__(256) void combine_kernel(
    const float* __restrict__ feat_prev, const float* __restrict__ feat_cur,
    const int* __restrict__ knn_idx, float* __restrict__ out,
    int n_cur, int c4)
{
    const int w = blockIdx.x * 4 + (threadIdx.x >> 6);
    const int lane = threadIdx.x & 63;
    const int q = w >> 2;
    const int jg = (w & 3) * 4;
    if (q >= n_cur) return;

    int nb[4];
#pragma unroll
    for (int j = 0; j < 4; ++j)
        nb[j] = knn_idx[q * KNN + jg + j];

    const vfloat4* pbase = (const vfloat4*)feat_prev;
    const vfloat4* crow  = (const vfloat4*)feat_cur + (size_t)q * c4;
    const int c8 = 2 * c4;

    for (int i = lane; i < c4; i += 64) {
        const vfloat4 c = crow[i];
        vfloat4 p[4];
#pragma unroll
        for (int j = 0; j < 4; ++j)
            p[j] = pbase[(size_t)nb[j] * c4 + i];

#pragma unroll
        for (int j = 0; j < 4; ++j) {
            vfloat4* orow = (vfloat4*)out + (size_t)(q * KNN + jg + j) * c8;
            __builtin_nontemporal_store(p[j] - c, orow + i);
            __builtin_nontemporal_store(c, orow + c4 + i);
        }
    }
}

extern "C" void kernel_launch(void* const* d_in, const int* in_sizes, int n_in,
                              void* d_out, int out_size, void* d_ws, size_t ws_size,
                              hipStream_t stream) {
    const float* xyz_prev  = (const float*)d_in[0];
    const float* xyz_cur   = (const float*)d_in[1];
    const float* feat_prev = (const float*)d_in[2];
    const float* feat_cur  = (const float*)d_in[3];
    float* out = (float*)d_out;

    const int n_prev = in_sizes[0] / 3;
    const int n_cur  = in_sizes[1] / 3;
    const int C      = in_sizes[2] / n_prev;   // 256

    // d_ws layout: [0, 16*n_prev) packed (x,y,z,r2) table; then knn indices.
    vfloat4* P = (vfloat4*)d_ws;
    int* knn = (int*)((char*)d_ws + (size_t)n_prev * sizeof(vfloat4));

    prep_kernel<<<(n_prev + 255) / 256, 256, 0, stream>>>(xyz_prev, P, n_prev);

    const int knn_blocks = (n_cur + 3) / 4;    // 4 queries (waves) per block
    knn_kernel<<<knn_blocks, 256, 0, stream>>>(P, xyz_cur, knn, n_prev, n_cur);

    const int n_waves = n_cur * 4;             // 4 neighbor-rows per wave
    combine_kernel<<<(n_waves + 3) / 4, 256, 0, stream>>>(feat_prev, feat_cur,
                                                          knn, out, n_cur, C / 4);
}